// Round 17
// baseline (731.109 us; speedup 1.0000x reference)
//
#include <hip/hip_runtime.h>

#define XM 30
#define YM 30
#define CELLS (XM * YM)   // 900
#define NT 960
#define NW (NT / 64)      // 15 waves
#define NITERS 1500
#define PITERS 30
#define RW 32             // plane row width in float2; cell (i,j) -> (i+1)*RW + j+1
#define PSZ (RW * 32)     // 1024 float2 = 8 KB per plane (zero halo ring)

__device__ __forceinline__ float clamp01(float v) {
    return __builtin_amdgcn_fmed3f(v, 0.f, 1.f);  // fmin(fmax(v,0),1) for finite v
}

// Block-wide sum reduction. All threads must call; returns total to all.
__device__ __forceinline__ float block_reduce_sum(float v, float* red, float* scal) {
#pragma unroll
    for (int off = 32; off > 0; off >>= 1)
        v += __shfl_down(v, off, 64);
    const int lane = threadIdx.x & 63;
    const int wid = threadIdx.x >> 6;
    if (lane == 0) red[wid] = v;
    __syncthreads();
    if (threadIdx.x == 0) {
        float s = 0.f;
#pragma unroll
        for (int w = 0; w < NW; ++w) s += red[w];
        scal[0] = s;
    }
    __syncthreads();
    return scal[0];
}

// r16 math (598us, absmax 0.0) with fusable LDS addressing: padded-halo plane
// turns all 8 neighbor reads into base + compile-time offsets
// {0,1,2,32,34,64,65,66} -> SILoadStoreOptimizer emits 4x ds_read2_b64 and the
// per-read address VALU disappears. Same bytes, same 8B lane stride
// (conflict-free), same masks/math. Halo stays zero forever (only interior
// cells are written) == r16's dummy-zero-cell semantics.
__global__ __launch_bounds__(NT, 1) void pdhg_grid_lp(const float* __restrict__ weights,
                                                      float* __restrict__ out) {
    __shared__ float2 yA[PSZ];
    __shared__ float2 yB[PSZ];
    __shared__ float red[NW];
    __shared__ float scal[1];

    const int t = threadIdx.x;
    const bool act = (t < CELLS);
    const int i = t / YM;
    const int j = t % YM;
    const int pb = act ? ((i + 1) * RW + (j + 1)) : (RW + 1);
    const int B = pb - RW - 1;  // stencil up-left corner

    // dirs d0..d7 = (-1,-1)(-1,0)(-1,1)(0,-1)(0,1)(1,-1)(1,0)(1,1)
    // plane offsets from B:  0     1     2     32    34    64    65    66
    const bool vU = act && (i > 0), vD = act && (i < XM - 1);
    const bool vL = act && (j > 0), vR = act && (j < YM - 1);
    float msk[8];
    msk[0] = (vU && vL) ? 1.f : 0.f; msk[1] = vU ? 1.f : 0.f; msk[2] = (vU && vR) ? 1.f : 0.f;
    msk[3] = vL ? 1.f : 0.f;         msk[4] = vR ? 1.f : 0.f;
    msk[5] = (vD && vL) ? 1.f : 0.f; msk[6] = vD ? 1.f : 0.f; msk[7] = (vD && vR) ? 1.f : 0.f;

    const float c_int = act ? weights[t] : 0.f;

    for (int k = t; k < PSZ; k += NT) {
        yA[k] = make_float2(0.f, 0.f);
        yB[k] = make_float2(0.f, 0.f);
    }
    __syncthreads();

#define RD8(SRC, YN)                                                  \
    {                                                                 \
        const float2* Bp = &SRC[B];                                   \
        YN[0] = Bp[0];  YN[1] = Bp[1];  YN[2] = Bp[2];                \
        YN[3] = Bp[32]; YN[4] = Bp[34];                               \
        YN[5] = Bp[64]; YN[6] = Bp[65]; YN[7] = Bp[66];               \
    }

    // ---------------- power iteration for L = ||A||_2 (exact r16 math) -------
    const float v0 = 1.0f / 88.0f;  // 1/sqrt(7744)
    float v_int = act ? v0 : 0.f;
    float vo8[8], vi8[8];
#pragma unroll
    for (int d = 0; d < 8; ++d) { vo8[d] = msk[d] * v0; vi8[d] = msk[d] * v0; }

    float L = 1.f;
    for (int it = 0; it <= PITERS; ++it) {
        float inc = 0.f, outg = 0.f;
#pragma unroll
        for (int d = 0; d < 8; ++d) { inc += vi8[d]; outg += vo8[d]; }
        const float u_in = v_int - inc;
        const float u_out = outg - v_int;

        if (it == PITERS) {
            const float p = u_in * u_in + u_out * u_out;
            L = sqrtf(block_reduce_sum(p, red, scal));
            break;
        }

        if (act) yA[pb] = make_float2(u_in, u_out);
        __syncthreads();

        float2 un[8];
        RD8(yA, un);

        const float w_int = u_in - u_out;
        float wo8[8], wi8[8];
#pragma unroll
        for (int d = 0; d < 8; ++d) {
            wo8[d] = msk[d] * (u_out - un[d].x);  // tail u_out(t), head u_in(nbr)
            wi8[d] = msk[d] * (un[d].y - u_in);   // tail u_out(nbr), head u_in(t)
        }
        // norm counts each edge ONCE: internal + negative-dir (owned) replicas
        float p = w_int * w_int;
#pragma unroll
        for (int d = 0; d < 4; ++d) p += wo8[d] * wo8[d] + wi8[d] * wi8[d];
        const float rn = 1.f / sqrtf(block_reduce_sum(p, red, scal));
        v_int = w_int * rn;
#pragma unroll
        for (int d = 0; d < 8; ++d) { vo8[d] = wo8[d] * rn; vi8[d] = wi8[d] * rn; }
        // plane reuse safe: reads precede the reduce's first barrier; next
        // publish follows its last barrier.
    }

    const float tau = 0.95f / L;
    const float sigma = tau;
    float tvv[8];
#pragma unroll
    for (int d = 0; d < 8; ++d) tvv[d] = msk[d] * tau;  // invalid edges pinned at 0

    // ---------------- PDHG main loop: 1 barrier / iteration ----------------
    float x_int = 0.f, y_in = 0.f, y_out = 0.f;
    float xo8[8] = {0.f, 0.f, 0.f, 0.f, 0.f, 0.f, 0.f, 0.f};
    float xi8[8] = {0.f, 0.f, 0.f, 0.f, 0.f, 0.f, 0.f, 0.f};
    float SolO = 0.f, SolI = 0.f;  // prev-iter edge-x sums (x starts at 0)
    const float sb_in = (t == 0) ? sigma : 0.f;            // sigma * b[source]
    const float sb_out = (t == CELLS - 1) ? -sigma : 0.f;  // sigma * b[sink]

    // re-zero plane A interior (power left u there); halo untouched-zero
    for (int k = t; k < PSZ; k += NT) yA[k] = make_float2(0.f, 0.f);
    __syncthreads();

    // Flow sums via prev-sum identity (r16-proven):
    //   sum_d (2*x_new[d] - x_old[d]) = 2*sum_d x_new[d] - sum_d x_old[d]
#define STEP(SRC, DST)                                                        \
    {                                                                         \
        float2 yn[8];                                                         \
        RD8(SRC, yn);                                                         \
        const float g = c_int + (y_in - y_out);                               \
        const float xn = clamp01(fmaf(-tau, g, x_int));                       \
        const float xb_int = fmaf(2.f, xn, -x_int);                           \
        x_int = xn;                                                           \
        float so = 0.f, si = 0.f;                                             \
        _Pragma("unroll") for (int d = 0; d < 8; ++d) {                       \
            const float go = y_out - yn[d].x;                                 \
            const float xno = clamp01(fmaf(-tvv[d], go, xo8[d]));             \
            so += xno; xo8[d] = xno;                                          \
            const float gi = yn[d].y - y_in;                                  \
            const float xni = clamp01(fmaf(-tvv[d], gi, xi8[d]));             \
            si += xni; xi8[d] = xni;                                          \
        }                                                                     \
        const float incb = fmaf(2.f, si, -SolI);                              \
        const float outb = fmaf(2.f, so, -SolO);                              \
        SolI = si; SolO = so;                                                 \
        y_in += sigma * (xb_int - incb) - sb_in;                              \
        y_out += sigma * (outb - xb_int) - sb_out;                            \
        if (act) DST[pb] = make_float2(y_in, y_out);                          \
        __syncthreads();                                                      \
    }

    for (int it = 0; it < NITERS / 2; ++it) {
        STEP(yA, yB)
        STEP(yB, yA)
    }

    if (act) out[t] = x_int;
}

extern "C" void kernel_launch(void* const* d_in, const int* in_sizes, int n_in,
                              void* d_out, int out_size, void* d_ws, size_t ws_size,
                              hipStream_t stream) {
    const float* weights = (const float*)d_in[0];  // (30,30) f32
    // d_in[1] (dense A) and d_in[2] (b) unused: incidence rebuilt from index math;
    // algorithm is equivariant under edge relabeling (v0 constant, x0=y0=0).
    float* out = (float*)d_out;  // 900 f32
    (void)in_sizes; (void)n_in; (void)out_size; (void)d_ws; (void)ws_size;

    hipLaunchKernelGGL(pdhg_grid_lp, dim3(1), dim3(NT), 0, stream, weights, out);
}

// Round 18
// 598.738 us; speedup vs baseline: 1.2211x; 1.2211x over previous
//
#include <hip/hip_runtime.h>

#define XM 30
#define YM 30
#define CELLS (XM * YM)   // 900
#define NT 960
#define NW (NT / 64)      // 15 waves
#define NITERS 1500
#define PITERS 30

__device__ __forceinline__ float clamp01(float v) {
    return __builtin_amdgcn_fmed3f(v, 0.f, 1.f);  // fmin(fmax(v,0),1) for finite v
}

// Block-wide sum reduction. All threads must call; returns total to all.
__device__ __forceinline__ float block_reduce_sum(float v, float* red, float* scal) {
#pragma unroll
    for (int off = 32; off > 0; off >>= 1)
        v += __shfl_down(v, off, 64);
    const int lane = threadIdx.x & 63;
    const int wid = threadIdx.x >> 6;
    if (lane == 0) red[wid] = v;
    __syncthreads();
    if (threadIdx.x == 0) {
        float s = 0.f;
#pragma unroll
        for (int w = 0; w < NW; ++w) s += red[w];
        scal[0] = s;
    }
    __syncthreads();
    return scal[0];
}

// r16 verbatim (best measured: 598us, absmax 0.0). Redundant-edge scheme:
// every cell updates ALL its incident edge-x values locally (replicas of every
// cross-thread edge stay bitwise identical: same IEEE exprs on identically
// published y bits). Only y is communicated: 8 scattered ds_read_b64 + 1
// ds_write_b64 per cell per iteration (consecutive lanes -> consecutive
// addresses, 2 lanes/bank = free), one barrier per iteration via
// double-buffered y planes. Index CELLS = dummy zero cell for borders.
// r17 proved read2-fusion REGRESSES (+43% bank conflicts); keep scattered b64.
__global__ __launch_bounds__(NT, 1) void pdhg_grid_lp(const float* __restrict__ weights,
                                                      float* __restrict__ out) {
    __shared__ float2 ybuf0[CELLS + 1];
    __shared__ float2 ybuf1[CELLS + 1];
    __shared__ float red[NW];
    __shared__ float scal[1];

    const int t = threadIdx.x;
    const bool act = (t < CELLS);
    const int i = t / YM;
    const int j = t % YM;

    const int DP[8] = {-1, -1, -1, 0, 0, 1, 1, 1};
    const int DQ[8] = {-1, 0, 1, -1, 1, -1, 0, 1};

    int nbr[8];
    float msk[8];
#pragma unroll
    for (int d = 0; d < 8; ++d) {
        const int ii = i + DP[d], jj = j + DQ[d];
        const bool ok = act && (ii >= 0) && (ii < XM) && (jj >= 0) && (jj < YM);
        msk[d] = ok ? 1.f : 0.f;
        nbr[d] = ok ? (ii * YM + jj) : CELLS;  // invalid -> dummy zero cell
    }
    const float c_int = act ? weights[t] : 0.f;

    if (t == 0) {
        ybuf0[CELLS] = make_float2(0.f, 0.f);
        ybuf1[CELLS] = make_float2(0.f, 0.f);
    }

    // ---------------- power iteration for L = ||A||_2 (exact r8 math) --------
    // v0 = ones/sqrt(V), V = 7744 = 88^2.
    const float v0 = 1.0f / 88.0f;
    float v_int = act ? v0 : 0.f;
    float vo8[8], vi8[8];
#pragma unroll
    for (int d = 0; d < 8; ++d) { vo8[d] = msk[d] * v0; vi8[d] = msk[d] * v0; }

    float L = 1.f;
    for (int it = 0; it <= PITERS; ++it) {
        float inc = 0.f, outg = 0.f;
#pragma unroll
        for (int d = 0; d < 8; ++d) { inc += vi8[d]; outg += vo8[d]; }
        const float u_in = v_int - inc;
        const float u_out = outg - v_int;

        if (it == PITERS) {
            const float p = u_in * u_in + u_out * u_out;
            L = sqrtf(block_reduce_sum(p, red, scal));
            break;
        }

        if (act) ybuf0[t] = make_float2(u_in, u_out);
        __syncthreads();

        float2 un[8];
#pragma unroll
        for (int d = 0; d < 8; ++d) un[d] = ybuf0[nbr[d]];

        const float w_int = u_in - u_out;
        float wo8[8], wi8[8];
#pragma unroll
        for (int d = 0; d < 8; ++d) {
            wo8[d] = msk[d] * (u_out - un[d].x);  // tail u_out(t), head u_in(nbr)
            wi8[d] = msk[d] * (un[d].y - u_in);   // tail u_out(nbr), head u_in(t)
        }
        // norm counts each edge ONCE: internal + negative-dir (owned) replicas
        float p = w_int * w_int;
#pragma unroll
        for (int d = 0; d < 4; ++d) p += wo8[d] * wo8[d] + wi8[d] * wi8[d];
        const float rn = 1.f / sqrtf(block_reduce_sum(p, red, scal));
        v_int = w_int * rn;
#pragma unroll
        for (int d = 0; d < 8; ++d) { vo8[d] = wo8[d] * rn; vi8[d] = wi8[d] * rn; }
    }

    const float tau = 0.95f / L;
    const float sigma = tau;
    float tvv[8];
#pragma unroll
    for (int d = 0; d < 8; ++d) tvv[d] = msk[d] * tau;  // invalid edges pinned at 0

    // ---------------- PDHG main loop: 1 barrier / iteration ----------------
    float x_int = 0.f, y_in = 0.f, y_out = 0.f;
    float xo8[8] = {0.f, 0.f, 0.f, 0.f, 0.f, 0.f, 0.f, 0.f};
    float xi8[8] = {0.f, 0.f, 0.f, 0.f, 0.f, 0.f, 0.f, 0.f};
    float SolO = 0.f, SolI = 0.f;  // prev-iter edge-x sums (x starts at 0)
    const float sb_in = (t == 0) ? sigma : 0.f;            // sigma * b[source]
    const float sb_out = (t == CELLS - 1) ? -sigma : 0.f;  // sigma * b[sink]

    if (act) ybuf0[t] = make_float2(0.f, 0.f);
    __syncthreads();

    // Flow sums via prev-sum identity (r9/r10-proven):
    //   sum_d (2*x_new[d] - x_old[d]) = 2*sum_d x_new[d] - sum_d x_old[d]
    // with sum_d x_old[d] carried from the previous iteration.
#define STEP(SRC, DST)                                                        \
    {                                                                         \
        float2 yn[8];                                                         \
        _Pragma("unroll") for (int d = 0; d < 8; ++d) yn[d] = SRC[nbr[d]];    \
        const float g = c_int + (y_in - y_out);                               \
        const float xn = clamp01(fmaf(-tau, g, x_int));                       \
        const float xb_int = fmaf(2.f, xn, -x_int);                           \
        x_int = xn;                                                           \
        float so = 0.f, si = 0.f;                                             \
        _Pragma("unroll") for (int d = 0; d < 8; ++d) {                       \
            const float go = y_out - yn[d].x;                                 \
            const float xno = clamp01(fmaf(-tvv[d], go, xo8[d]));             \
            so += xno; xo8[d] = xno;                                          \
            const float gi = yn[d].y - y_in;                                  \
            const float xni = clamp01(fmaf(-tvv[d], gi, xi8[d]));             \
            si += xni; xi8[d] = xni;                                          \
        }                                                                     \
        const float incb = fmaf(2.f, si, -SolI);                              \
        const float outb = fmaf(2.f, so, -SolO);                              \
        SolI = si; SolO = so;                                                 \
        y_in += sigma * (xb_int - incb) - sb_in;                              \
        y_out += sigma * (outb - xb_int) - sb_out;                            \
        if (act) DST[t] = make_float2(y_in, y_out);                           \
        __syncthreads();                                                      \
    }

    for (int it = 0; it < NITERS / 2; ++it) {
        STEP(ybuf0, ybuf1)
        STEP(ybuf1, ybuf0)
    }

    if (act) out[t] = x_int;
}

extern "C" void kernel_launch(void* const* d_in, const int* in_sizes, int n_in,
                              void* d_out, int out_size, void* d_ws, size_t ws_size,
                              hipStream_t stream) {
    const float* weights = (const float*)d_in[0];  // (30,30) f32
    // d_in[1] (dense A) and d_in[2] (b) unused: incidence rebuilt from index math;
    // algorithm is equivariant under edge relabeling (v0 constant, x0=y0=0).
    float* out = (float*)d_out;  // 900 f32
    (void)in_sizes; (void)n_in; (void)out_size; (void)d_ws; (void)ws_size;

    hipLaunchKernelGGL(pdhg_grid_lp, dim3(1), dim3(NT), 0, stream, weights, out);
}